// Round 1
// baseline (266.369 us; speedup 1.0000x reference)
//
#include <hip/hip_runtime.h>

#define SIGMA 0.5f
#define BB 32
#define NVV 6890
#define NFF 13776
#define MAXC 8
#define NCC (NFF * MAXC)

__device__ __forceinline__ float3 loadv3(const float* __restrict__ p) {
    return make_float3(p[0], p[1], p[2]);
}

// Penetration of query triangle verts (q0,q1,q2) in the cone field of
// triangle (a0,a1,a2). Mirrors _cone_point2plane exactly (f32 math).
__device__ __forceinline__ float conePen(float3 a0, float3 a1, float3 a2,
                                         float3 q0, float3 q1, float3 q2) {
    const float third = 1.0f / 3.0f;
    float cx = (a0.x + a1.x + a2.x) * third;
    float cy = (a0.y + a1.y + a2.y) * third;
    float cz = (a0.z + a1.z + a2.z) * third;

    float e1x = a1.x - a0.x, e1y = a1.y - a0.y, e1z = a1.z - a0.z;
    float e2x = a2.x - a0.x, e2y = a2.y - a0.y, e2z = a2.z - a0.z;

    float nx = e1y * e2z - e1z * e2y;
    float ny = e1z * e2x - e1x * e2z;
    float nz = e1x * e2y - e1y * e2x;
    float nn = sqrtf(nx * nx + ny * ny + nz * nz) + 1e-8f;
    float inv = 1.0f / nn;
    nx *= inv; ny *= inv; nz *= inv;

    float pen = 0.0f;
    float3 q[3] = {q0, q1, q2};
#pragma unroll
    for (int v = 0; v < 3; ++v) {
        float dx = q[v].x - cx;
        float dy = q[v].y - cy;
        float dz = q[v].z - cz;
        float h = dx * nx + dy * ny + dz * nz;
        float r = sqrtf(dx * dx + dy * dy + dz * dz);
        float phi = fmaxf(SIGMA - r, 0.0f);
        pen += (h < 0.0f) ? phi * h * h : 0.0f;
    }
    return pen;
}

__global__ void init_kernel(float* __restrict__ accum) {
    accum[0] = 0.0f;
}

__global__ __launch_bounds__(256) void pen_kernel(
    const float* __restrict__ vertices,   // [B, NV, 3]
    const int*   __restrict__ faces,      // [NF, 3]
    const int2*  __restrict__ cidx,       // [B, NC] of (recv, intr)
    float* __restrict__ accum)
{
    const int i = blockIdx.x * blockDim.x + threadIdx.x;
    float pen = 0.0f;

    if (i < BB * NCC) {
        const int b = i / NCC;
        const int2 pr = cidx[i];
        if (pr.x >= 0) {                      // valid = recv_idx >= 0
            const int f0 = pr.x;
            const int f1 = pr.y < 0 ? 0 : pr.y;  // gather clamps with max(idx,0)
            const float* vb = vertices + (size_t)b * (NVV * 3);

            const int i0 = faces[f0 * 3 + 0];
            const int i1 = faces[f0 * 3 + 1];
            const int i2 = faces[f0 * 3 + 2];
            const int j0 = faces[f1 * 3 + 0];
            const int j1 = faces[f1 * 3 + 1];
            const int j2 = faces[f1 * 3 + 2];

            float3 a0 = loadv3(vb + (size_t)i0 * 3);
            float3 a1 = loadv3(vb + (size_t)i1 * 3);
            float3 a2 = loadv3(vb + (size_t)i2 * 3);
            float3 b0 = loadv3(vb + (size_t)j0 * 3);
            float3 b1 = loadv3(vb + (size_t)j1 * 3);
            float3 b2 = loadv3(vb + (size_t)j2 * 3);

            // symmetric: intruder verts in receiver field + vice versa
            pen = conePen(a0, a1, a2, b0, b1, b2)
                + conePen(b0, b1, b2, a0, a1, a2);
        }
    }

    // wave (64-lane) shuffle reduce
#pragma unroll
    for (int off = 32; off > 0; off >>= 1)
        pen += __shfl_down(pen, off, 64);

    __shared__ float smem[4];
    const int lane = threadIdx.x & 63;
    const int wv   = threadIdx.x >> 6;
    if (lane == 0) smem[wv] = pen;
    __syncthreads();
    if (threadIdx.x == 0) {
        atomicAdd(accum, smem[0] + smem[1] + smem[2] + smem[3]);
    }
}

__global__ void fin_kernel(const float* __restrict__ accum,
                           const float* __restrict__ weight,
                           float* __restrict__ out)
{
    out[0] = accum[0] * weight[0] * (1.0f / (float)BB);
}

extern "C" void kernel_launch(void* const* d_in, const int* in_sizes, int n_in,
                              void* d_out, int out_size, void* d_ws, size_t ws_size,
                              hipStream_t stream) {
    const float* vertices = (const float*)d_in[4];
    const float* weight   = (const float*)d_in[5];
    const int*   faces    = (const int*)d_in[6];
    const int2*  cidx     = (const int2*)d_in[7];

    float* accum = (float*)d_ws;   // re-poisoned each call; zero it ourselves
    float* out   = (float*)d_out;

    init_kernel<<<dim3(1), dim3(1), 0, stream>>>(accum);

    const int total  = BB * NCC;               // 3,526,656
    const int blocks = (total + 255) / 256;    // 13,776
    pen_kernel<<<dim3(blocks), dim3(256), 0, stream>>>(vertices, faces, cidx, accum);

    fin_kernel<<<dim3(1), dim3(1), 0, stream>>>(accum, weight, out);
}